// Round 4
// baseline (17006.747 us; speedup 1.0000x reference)
//
#include <hip/hip_runtime.h>
#include <hip/hip_bf16.h>
#include <cstdint>

typedef __hip_bfloat16 bf16;
typedef __attribute__((ext_vector_type(8))) short bf16x8v;   // 8 bf16 in 4 VGPRs
typedef __attribute__((ext_vector_type(4))) float f32x4;

#define NB 256          // persistent blocks (1 per CU; all co-resident)
#define TM1 64
#define BATCH 512

// output offsets (elements) in d_out, per reference return order
#define OUT_BEL  ((size_t)0)
#define OUT_PST  ((size_t)67108864)   // prior_states
#define OUT_PMU  ((size_t)75497472)   // prior_means
#define OUT_PSD  ((size_t)83886080)   // prior_std_devs
#define OUT_QST  ((size_t)92274688)   // posterior_states
#define OUT_QMU  ((size_t)100663296)  // posterior_means
#define OUT_QSD  ((size_t)109051904)  // posterior_std_devs

__device__ __forceinline__ void gload_lds16(const bf16* g, bf16* l) {
  __builtin_amdgcn_global_load_lds(
      (const __attribute__((address_space(1))) unsigned int*)g,
      (__attribute__((address_space(3))) unsigned int*)l, 16, 0, 0);
}

__device__ __forceinline__ unsigned short bfb(float f) {
  bf16 h = __float2bfloat16(f);
  return *reinterpret_cast<unsigned short*>(&h);
}

// device-scope grid barrier: monotone counter, target = (#barriers so far)*NB.
// Counter is zeroed by hipMemsetAsync before each kernel replay.
__device__ __forceinline__ void gbar(unsigned* cnt, unsigned target) {
  __syncthreads();
  if (threadIdx.x == 0) {
    __threadfence();   // release: write back this XCD's dirty L2 lines
    __hip_atomic_fetch_add(cnt, 1u, __ATOMIC_RELAXED, __HIP_MEMORY_SCOPE_AGENT);
    while (__hip_atomic_load(cnt, __ATOMIC_RELAXED, __HIP_MEMORY_SCOPE_AGENT) < target)
      __builtin_amdgcn_s_sleep(2);
    __threadfence();   // acquire: invalidate L1/L2 so fresh data is read
  }
  __syncthreads();
}

// ---------------------------------------------------------------------------
// one GEMM output tile: C[M,N] = A[M,K](bf16,row) @ B[N,K](bf16,row)^T + bias
// 2-phase LDS double-buffer (stage t+1 issued before compute t, one sync/iter)
// mode 0: C fp32. mode 1: C bf16 + relu. job decode: m fastest.
// ---------------------------------------------------------------------------
template<int BM, int BN>
__device__ void gemm_tile(const bf16* __restrict__ A, const bf16* __restrict__ B,
                          const float* __restrict__ bias, void* __restrict__ C,
                          int N, int K, int nm, int mode, int job, int tid,
                          char* pool)
{
  bf16 (*sA)[BM * 64] = (bf16(*)[BM * 64])pool;
  bf16 (*sB)[BN * 64] = (bf16(*)[BN * 64])(pool + 2 * BM * 64 * 2);

  const int m0 = (job % nm) * BM;
  const int n0 = (job / nm) * BN;
  const int lane = tid & 63;
  const int wid = tid >> 6;
  const int wm = wid >> 1, wn = wid & 1;
  const int lr = lane & 15;
  const int ko = (lane >> 4) * 8;
  constexpr int WMt = BM / 2, WNt = BN / 2;
  constexpr int MR = WMt / 16, NR = WNt / 16;

  const bf16* Abase = A + (size_t)m0 * K;
  const bf16* Bbase = B + (size_t)n0 * K;

  auto stage = [&](int buf, int k0) {
    #pragma unroll
    for (int i = 0; i < BM / 32; ++i) {
      int c = i * 256 + tid;
      gload_lds16(Abase + (size_t)(c >> 3) * K + k0 + (c & 7) * 8, &sA[buf][c * 8]);
    }
    #pragma unroll
    for (int i = 0; i < BN / 32; ++i) {
      int c = i * 256 + tid;
      gload_lds16(Bbase + (size_t)(c >> 3) * K + k0 + (c & 7) * 8, &sB[buf][c * 8]);
    }
  };

  f32x4 acc[MR][NR] = {};
  __syncthreads();                        // pool free (prev user done)
  stage(0, 0);
  __syncthreads();
  const int nk = K >> 6;
  for (int it = 0; it < nk; ++it) {
    const int cur = it & 1;
    if (it + 1 < nk) stage(cur ^ 1, (it + 1) << 6);
    #pragma unroll
    for (int kk = 0; kk < 2; ++kk) {
      bf16x8v af[MR], bfv[NR];
      #pragma unroll
      for (int m = 0; m < MR; ++m)
        af[m] = *(const bf16x8v*)&sA[cur][(wm * WMt + m * 16 + lr) * 64 + kk * 32 + ko];
      #pragma unroll
      for (int n = 0; n < NR; ++n)
        bfv[n] = *(const bf16x8v*)&sB[cur][(wn * WNt + n * 16 + lr) * 64 + kk * 32 + ko];
      #pragma unroll
      for (int m = 0; m < MR; ++m)
        #pragma unroll
        for (int n = 0; n < NR; ++n)
          acc[m][n] = __builtin_amdgcn_mfma_f32_16x16x32_bf16(af[m], bfv[n], acc[m][n], 0, 0, 0);
    }
    __syncthreads();
  }

  const int r0 = (lane >> 4) * 4;
  #pragma unroll
  for (int m = 0; m < MR; ++m) {
    #pragma unroll
    for (int n = 0; n < NR; ++n) {
      int gc = n0 + wn * WNt + n * 16 + lr;
      float bv = bias[gc];
      #pragma unroll
      for (int r = 0; r < 4; ++r) {
        int gr = m0 + wm * WMt + m * 16 + r0 + r;
        float v = acc[m][n][r] + bv;
        if (mode == 1)
          ((bf16*)C)[(size_t)gr * N + gc] = __float2bfloat16(v > 0.f ? v : 0.f);
        else
          ((float*)C)[(size_t)gr * N + gc] = v;
      }
    }
  }
}

// ---------------------------------------------------------------------------
// fused W2p GEMM (512x512, K=2048) + posterior softplus/rsample epilogue.
// 32 jobs: mb 0..7 (64 rows), nl 0..3 (cols nl*64..+63 of BOTH loc and raw).
// ---------------------------------------------------------------------------
__device__ void w2p_tile(const bf16* __restrict__ hq, const bf16* __restrict__ W2pT,
                         const float* __restrict__ b2p, const float* __restrict__ eps,
                         float* __restrict__ o_mu, float* __restrict__ o_sd,
                         float* __restrict__ o_st,
                         const float* __restrict__ nt_next,
                         const float* __restrict__ act_next,
                         bf16* __restrict__ xcat, int make_xcat,
                         int blk, int tid, char* pool)
{
  constexpr int K = 2048, NK = K / 64;
  const int mb = blk & 7, nl = blk >> 3;
  const int m0 = mb * 64;

  bf16 (*sA)[64 * 64]  = (bf16(*)[64 * 64])pool;             // 2 x 8KB
  bf16 (*sB)[128 * 64] = (bf16(*)[128 * 64])(pool + 16384);  // 2 x 16KB
  float* tile = (float*)pool;                                 // 32KB reuse

  const int lane = tid & 63;
  const int wid = tid >> 6;
  const int wm = wid >> 1, wn = wid & 1;
  const int lr = lane & 15;
  const int ko = (lane >> 4) * 8;

  const bf16* Abase = hq + (size_t)m0 * K;

  auto stage = [&](int buf, int k0) {
    #pragma unroll
    for (int i = 0; i < 2; ++i) {
      int c = i * 256 + tid;
      gload_lds16(Abase + (size_t)(c >> 3) * K + k0 + (c & 7) * 8, &sA[buf][c * 8]);
    }
    #pragma unroll
    for (int i = 0; i < 4; ++i) {
      int c = i * 256 + tid;
      int row = c >> 3;
      int grow = (row < 64) ? (nl * 64 + row) : (192 + nl * 64 + row);
      gload_lds16(W2pT + (size_t)grow * K + k0 + (c & 7) * 8, &sB[buf][c * 8]);
    }
  };

  f32x4 acc[2][4] = {};
  __syncthreads();
  stage(0, 0);
  __syncthreads();
  for (int it = 0; it < NK; ++it) {
    const int cur = it & 1;
    if (it + 1 < NK) stage(cur ^ 1, (it + 1) << 6);
    #pragma unroll
    for (int kk = 0; kk < 2; ++kk) {
      bf16x8v af[2], bfv[4];
      #pragma unroll
      for (int m = 0; m < 2; ++m)
        af[m] = *(const bf16x8v*)&sA[cur][(wm * 32 + m * 16 + lr) * 64 + kk * 32 + ko];
      #pragma unroll
      for (int n = 0; n < 4; ++n)
        bfv[n] = *(const bf16x8v*)&sB[cur][(wn * 64 + n * 16 + lr) * 64 + kk * 32 + ko];
      #pragma unroll
      for (int m = 0; m < 2; ++m)
        #pragma unroll
        for (int n = 0; n < 4; ++n)
          acc[m][n] = __builtin_amdgcn_mfma_f32_16x16x32_bf16(af[m], bfv[n], acc[m][n], 0, 0, 0);
    }
    __syncthreads();
  }

  const int r0 = (lane >> 4) * 4;
  #pragma unroll
  for (int m = 0; m < 2; ++m)
    #pragma unroll
    for (int n = 0; n < 4; ++n) {
      int tc = wn * 64 + n * 16 + lr;
      #pragma unroll
      for (int r = 0; r < 4; ++r)
        tile[(wm * 32 + m * 16 + r0 + r) * 128 + tc] = acc[m][n][r];
    }
  __syncthreads();

  for (int e = tid; e < 4096; e += 256) {
    int rr = e >> 6, cc = e & 63;
    int b = m0 + rr;
    int j = nl * 64 + cc;
    float loc = tile[rr * 128 + cc] + b2p[j];
    float raw = tile[rr * 128 + 64 + cc] + b2p[256 + j];
    float sp = (raw > 20.f) ? raw : log1pf(__expf(raw));
    float scale = sp + 0.1f;
    float st = loc + scale * eps[(size_t)b * 256 + j];
    o_mu[(size_t)b * 256 + j] = loc;
    o_sd[(size_t)b * 256 + j] = scale;
    o_st[(size_t)b * 256 + j] = st;
    if (make_xcat) {
      xcat[(size_t)b * 320 + j] = __float2bfloat16(st * nt_next[b]);
      if (nl == 0)
        xcat[(size_t)b * 320 + 256 + cc] = __float2bfloat16(act_next[(size_t)b * 64 + cc]);
    }
  }
}

// ---------------------------------------------------------------------------
// weight transpose phase: src fp32 [K,N] -> dst bf16 [N,K], grid-stride tiles
// ---------------------------------------------------------------------------
__device__ void transpose_phase(const float* __restrict__ src, bf16* __restrict__ dst,
                                int K, int N, int bid, int tid, float* t /*32x33*/)
{
  const int ntile = (K / 32) * (N / 32);
  const int tx = tid & 31, ty = tid >> 5;   // 32 x 8
  for (int it = bid; it < ntile; it += NB) {
    int kt = it % (K / 32), nt = it / (K / 32);
    int k0 = kt * 32, n0 = nt * 32;
    __syncthreads();
    #pragma unroll
    for (int i = 0; i < 32; i += 8)
      t[(ty + i) * 33 + tx] = src[(size_t)(k0 + ty + i) * N + n0 + tx];
    __syncthreads();
    #pragma unroll
    for (int i = 0; i < 32; i += 8)
      dst[(size_t)(n0 + ty + i) * K + k0 + tx] = __float2bfloat16(t[tx * 33 + ty + i]);
  }
}

__device__ __forceinline__ float sigmoidf_(float x) { return 1.f / (1.f + __expf(-x)); }

__device__ __forceinline__ float gru1(float ir, float hr, float iz, float hz,
                                      float in_, float hn, float bo)
{
  float r = sigmoidf_(ir + hr);
  float z = sigmoidf_(iz + hz);
  float n = tanhf(in_ + r * hn);
  return (1.f - z) * n + z * bo;
}

struct Args {
  const float *prev_state, *actions, *prev_belief, *obs_emb, *nonterm;
  const float *W_embed, *b_embed, *Wi, *bi, *Wh, *bh;
  const float *W1, *b1, *W2, *b2, *W1p, *b1p, *W2p, *b2p;
  const float *eps_p, *eps_q;
  bf16 *WembT, *WiT, *WhT, *W1T, *W2T, *W1pT, *W2pT;
  float* belief_f32; bf16 *belief_b16, *xcat, *hidden;
  float *gi, *gh; bf16 *hqcat, *hq, *belA, *hp; float* yp;
  float* out;
  unsigned* cnt;
};

// ---------------------------------------------------------------------------
__global__ __launch_bounds__(256) void mega(Args a)
{
  extern __shared__ char pool[];        // 64 KB
  const int bid = blockIdx.x;
  const int tid = threadIdx.x;
  const int sj = ((bid & 7) << 5) | (bid >> 3);   // XCD-grouped job id
  unsigned tgt = 0;

  // ---- P0: weight transposes + init belief/xcat ----
  transpose_phase(a.W_embed, a.WembT, 320, 2048, bid, tid, (float*)pool);
  transpose_phase(a.Wi,  a.WiT,  2048, 6144, bid, tid, (float*)pool);
  transpose_phase(a.Wh,  a.WhT,  2048, 6144, bid, tid, (float*)pool);
  transpose_phase(a.W1,  a.W1T,  2048, 2048, bid, tid, (float*)pool);
  transpose_phase(a.W2,  a.W2T,  2048, 512,  bid, tid, (float*)pool);
  transpose_phase(a.W1p, a.W1pT, 3072, 2048, bid, tid, (float*)pool);
  transpose_phase(a.W2p, a.W2pT, 2048, 512,  bid, tid, (float*)pool);
  for (int i = bid * 256 + tid; i < 512 * 2048; i += NB * 256) {
    float v = a.prev_belief[i];
    a.belief_f32[i] = v;
    a.belief_b16[i] = __float2bfloat16(v);
  }
  for (int i = bid * 256 + tid; i < 512 * 320; i += NB * 256) {
    int b = i / 320, c = i - b * 320;
    float v = (c < 256) ? a.prev_state[b * 256 + c] * a.nonterm[b]
                        : a.actions[b * 64 + (c - 256)];
    a.xcat[i] = __float2bfloat16(v);
  }
  gbar(a.cnt, tgt += NB);

  // ---- P1: hidden_0 = relu(xcat @ WembT + b_embed) ----
  gemm_tile<64, 64>(a.xcat, a.WembT, a.b_embed, a.hidden, 2048, 320, 8, 1, sj, tid, pool);
  gbar(a.cnt, tgt += NB);

  for (int t = 0; t < TM1; ++t) {
    // ---- GIGH: gi = hidden@WiT+bi ; gh = belief@WhT+bh ----
    gemm_tile<128, 96>(a.hidden, a.WiT, a.bi, a.gi, 6144, 2048, 4, 0, sj, tid, pool);
    gemm_tile<128, 96>(a.belief_b16, a.WhT, a.bh, a.gh, 6144, 2048, 4, 0, sj, tid, pool);
    gbar(a.cnt, tgt += NB);

    // ---- gru elementwise ----
    {
      const float* obs_t = a.obs_emb + (size_t)t * 512 * 1024;
      float* out_bel = a.out + OUT_BEL + (size_t)t * 512 * 2048;
      for (int i = bid * 256 + tid; i < 512 * 2048 / 4; i += NB * 256) {
        int b = i >> 9;
        int c = (i & 511) * 4;
        size_t gb = (size_t)b * 6144;
        float4 ir = *(const float4*)&a.gi[gb + c];
        float4 iz = *(const float4*)&a.gi[gb + 2048 + c];
        float4 in_ = *(const float4*)&a.gi[gb + 4096 + c];
        float4 hr = *(const float4*)&a.gh[gb + c];
        float4 hz = *(const float4*)&a.gh[gb + 2048 + c];
        float4 hn = *(const float4*)&a.gh[gb + 4096 + c];
        float4 bo = *(const float4*)&a.belief_f32[(size_t)b * 2048 + c];
        float4 nb;
        nb.x = gru1(ir.x, hr.x, iz.x, hz.x, in_.x, hn.x, bo.x);
        nb.y = gru1(ir.y, hr.y, iz.y, hz.y, in_.y, hn.y, bo.y);
        nb.z = gru1(ir.z, hr.z, iz.z, hz.z, in_.z, hn.z, bo.z);
        nb.w = gru1(ir.w, hr.w, iz.w, hz.w, in_.w, hn.w, bo.w);
        *(float4*)&a.belief_f32[(size_t)b * 2048 + c] = nb;
        *(float4*)&out_bel[(size_t)b * 2048 + c] = nb;
        ushort4 u; u.x = bfb(nb.x); u.y = bfb(nb.y); u.z = bfb(nb.z); u.w = bfb(nb.w);
        *(ushort4*)&a.belief_b16[(size_t)b * 2048 + c] = u;
        *(ushort4*)&a.hqcat[(size_t)b * 3072 + c] = u;
        if ((i & 511) < 256) {
          float4 ov = *(const float4*)&obs_t[(size_t)b * 1024 + c];
          ushort4 uo; uo.x = bfb(ov.x); uo.y = bfb(ov.y); uo.z = bfb(ov.z); uo.w = bfb(ov.w);
          *(ushort4*)&a.hqcat[(size_t)b * 3072 + 2048 + c] = uo;
        }
      }
    }
    gbar(a.cnt, tgt += NB);

    // ---- W1p: hq = relu(hqcat @ W1pT + b1p), K=3072 ----
    gemm_tile<64, 64>(a.hqcat, a.W1pT, a.b1p, a.hq, 2048, 3072, 8, 1, sj, tid, pool);
    gbar(a.cnt, tgt += NB);

    // ---- fused W2p + posterior sample + next xcat ----
    {
      int tn = (t < TM1 - 1) ? t + 1 : t;
      if (bid < 32)
        w2p_tile(a.hq, a.W2pT, a.b2p,
                 a.eps_q + (size_t)t * 512 * 256,
                 a.out + OUT_QMU + (size_t)t * 512 * 256,
                 a.out + OUT_QSD + (size_t)t * 512 * 256,
                 a.out + OUT_QST + (size_t)t * 512 * 256,
                 a.nonterm + (size_t)tn * 512,
                 a.actions + (size_t)tn * 512 * 64,
                 a.xcat, (t < TM1 - 1) ? 1 : 0, bid, tid, pool);
    }
    gbar(a.cnt, tgt += NB);

    // ---- embed: hidden_{t+1} = relu(xcat @ WembT + b_embed) ----
    if (t < TM1 - 1) {
      gemm_tile<64, 64>(a.xcat, a.WembT, a.b_embed, a.hidden, 2048, 320, 8, 1, sj, tid, pool);
      gbar(a.cnt, tgt += NB);
    }
  }

  // ---- batched prior: 8 chunks of 4096 rows ----
  for (int c = 0; c < 8; ++c) {
    const float* bsrc = a.out + OUT_BEL + (size_t)c * 4096 * 2048;
    for (int i = bid * 256 + tid; i < 4096 * 2048 / 4; i += NB * 256) {
      float4 v = *(const float4*)&bsrc[i * 4];
      ushort4 u; u.x = bfb(v.x); u.y = bfb(v.y); u.z = bfb(v.z); u.w = bfb(v.w);
      *(ushort4*)&a.belA[i * 4] = u;
    }
    gbar(a.cnt, tgt += NB);

    // hp = relu(belA @ W1T + b1): 512 jobs of 128x128, 2 rounds
    gemm_tile<128, 128>(a.belA, a.W1T, a.b1, a.hp, 2048, 2048, 32, 1, sj, tid, pool);
    gemm_tile<128, 128>(a.belA, a.W1T, a.b1, a.hp, 2048, 2048, 32, 1, sj + 256, tid, pool);
    gbar(a.cnt, tgt += NB);

    // yp = hp @ W2T + b2: 512 jobs of 64x64, 2 rounds
    gemm_tile<64, 64>(a.hp, a.W2T, a.b2, a.yp, 512, 2048, 64, 0, sj, tid, pool);
    gemm_tile<64, 64>(a.hp, a.W2T, a.b2, a.yp, 512, 2048, 64, 0, sj + 256, tid, pool);
    gbar(a.cnt, tgt += NB);

    for (int i = bid * 256 + tid; i < 4096 * 256; i += NB * 256) {
      int r = i >> 8, j = i & 255;
      float loc = a.yp[(size_t)r * 512 + j];
      float raw = a.yp[(size_t)r * 512 + 256 + j];
      float sp = (raw > 20.f) ? raw : log1pf(__expf(raw));
      float scale = sp + 0.1f;
      size_t o = (size_t)c * 4096 * 256 + i;
      a.out[OUT_PMU + o] = loc;
      a.out[OUT_PSD + o] = scale;
      a.out[OUT_PST + o] = loc + scale * a.eps_p[o];
    }
    gbar(a.cnt, tgt += NB);
  }
}

// ---------------------------------------------------------------------------
extern "C" void kernel_launch(void* const* d_in, const int* in_sizes, int n_in,
                              void* d_out, int out_size, void* d_ws, size_t ws_size,
                              hipStream_t stream)
{
  (void)in_sizes; (void)n_in; (void)out_size; (void)ws_size;
  Args a;
  a.prev_state = (const float*)d_in[0];
  a.actions    = (const float*)d_in[1];
  a.prev_belief= (const float*)d_in[2];
  a.obs_emb    = (const float*)d_in[3];
  a.nonterm    = (const float*)d_in[4];
  a.W_embed    = (const float*)d_in[5];
  a.b_embed    = (const float*)d_in[6];
  a.Wi         = (const float*)d_in[7];
  a.bi         = (const float*)d_in[8];
  a.Wh         = (const float*)d_in[9];
  a.bh         = (const float*)d_in[10];
  a.W1         = (const float*)d_in[11];
  a.b1         = (const float*)d_in[12];
  a.W2         = (const float*)d_in[13];
  a.b2         = (const float*)d_in[14];
  a.W1p        = (const float*)d_in[15];
  a.b1p        = (const float*)d_in[16];
  a.W2p        = (const float*)d_in[17];
  a.b2p        = (const float*)d_in[18];
  a.eps_p      = (const float*)d_in[19];
  a.eps_q      = (const float*)d_in[20];
  a.out        = (float*)d_out;

  char* ws = (char*)d_ws;
  size_t off = 0;
  auto alloc = [&](size_t bytes) -> char* {
    char* p = ws + off;
    off = (off + bytes + 255) & ~(size_t)255;
    return p;
  };
  a.cnt        = (unsigned*)alloc(256);
  a.WembT      = (bf16*)alloc((size_t)2048 * 320 * 2);
  a.WiT        = (bf16*)alloc((size_t)6144 * 2048 * 2);
  a.WhT        = (bf16*)alloc((size_t)6144 * 2048 * 2);
  a.W1T        = (bf16*)alloc((size_t)2048 * 2048 * 2);
  a.W2T        = (bf16*)alloc((size_t)512 * 2048 * 2);
  a.W1pT       = (bf16*)alloc((size_t)2048 * 3072 * 2);
  a.W2pT       = (bf16*)alloc((size_t)512 * 2048 * 2);
  a.belief_f32 = (float*)alloc((size_t)512 * 2048 * 4);
  a.belief_b16 = (bf16*)alloc((size_t)512 * 2048 * 2);
  a.xcat       = (bf16*)alloc((size_t)512 * 320 * 2);
  a.hidden     = (bf16*)alloc((size_t)512 * 2048 * 2);
  a.gi         = (float*)alloc((size_t)512 * 6144 * 4);
  a.gh         = (float*)alloc((size_t)512 * 6144 * 4);
  a.hqcat      = (bf16*)alloc((size_t)512 * 3072 * 2);
  a.hq         = (bf16*)alloc((size_t)512 * 2048 * 2);
  a.belA       = (bf16*)alloc((size_t)4096 * 2048 * 2);
  a.hp         = (bf16*)alloc((size_t)4096 * 2048 * 2);
  a.yp         = (float*)alloc((size_t)4096 * 512 * 4);

  hipMemsetAsync(a.cnt, 0, 256, stream);
  mega<<<NB, 256, 65536, stream>>>(a);
}

// Round 5
// 15287.277 us; speedup vs baseline: 1.1125x; 1.1125x over previous
//
#include <hip/hip_runtime.h>
#include <hip/hip_bf16.h>
#include <cstdint>

typedef __hip_bfloat16 bf16;
typedef __attribute__((ext_vector_type(8))) short bf16x8v;   // 8 bf16 in 4 VGPRs
typedef __attribute__((ext_vector_type(4))) float f32x4;

#define NB 256          // persistent blocks (1 per CU; all co-resident)
#define TM1 64
#define BATCH 512

// output offsets (elements) in d_out, per reference return order
#define OUT_BEL  ((size_t)0)
#define OUT_PST  ((size_t)67108864)   // prior_states
#define OUT_PMU  ((size_t)75497472)   // prior_means
#define OUT_PSD  ((size_t)83886080)   // prior_std_devs
#define OUT_QST  ((size_t)92274688)   // posterior_states
#define OUT_QMU  ((size_t)100663296)  // posterior_means
#define OUT_QSD  ((size_t)109051904)  // posterior_std_devs

__device__ __forceinline__ void gload_lds16(const bf16* g, bf16* l) {
  __builtin_amdgcn_global_load_lds(
      (const __attribute__((address_space(1))) unsigned int*)g,
      (__attribute__((address_space(3))) unsigned int*)l, 16, 0, 0);
}

__device__ __forceinline__ unsigned short bfb(float f) {
  bf16 h = __float2bfloat16(f);
  return *reinterpret_cast<unsigned short*>(&h);
}

// device-scope grid barrier: monotone counter, target = (#barriers so far)*NB.
// Counter is zeroed by hipMemsetAsync before each kernel replay.
__device__ __forceinline__ void gbar(unsigned* cnt, unsigned target) {
  __syncthreads();
  if (threadIdx.x == 0) {
    __threadfence();   // release: drain + write back dirty lines
    __hip_atomic_fetch_add(cnt, 1u, __ATOMIC_RELAXED, __HIP_MEMORY_SCOPE_AGENT);
    while (__hip_atomic_load(cnt, __ATOMIC_RELAXED, __HIP_MEMORY_SCOPE_AGENT) < target)
      __builtin_amdgcn_s_sleep(8);
    __threadfence();   // acquire: invalidate stale cached lines
  }
  __syncthreads();
}

// ---------------------------------------------------------------------------
// one GEMM output tile: C[M,N] = A[M,K](bf16,row) @ B[N,K](bf16,row)^T + bias
// 2-phase LDS double-buffer (stage t+1 issued before compute t, one sync/iter)
// T2 bank-conflict fix: 16B-chunk index XOR'd with (row&7) — applied on the
// GLOBAL source address at stage time (LDS dest stays linear, rule #21) and
// on the ds_read address at use time.
// mode 0: C fp32. mode 1: C bf16 + relu. job decode: m fastest.
// ---------------------------------------------------------------------------
template<int BM, int BN>
__device__ void gemm_tile(const bf16* __restrict__ A, const bf16* __restrict__ B,
                          const float* __restrict__ bias, void* __restrict__ C,
                          int N, int K, int nm, int mode, int job, int tid,
                          char* pool)
{
  bf16 (*sA)[BM * 64] = (bf16(*)[BM * 64])pool;
  bf16 (*sB)[BN * 64] = (bf16(*)[BN * 64])(pool + 2 * BM * 64 * 2);

  const int m0 = (job % nm) * BM;
  const int n0 = (job / nm) * BN;
  const int lane = tid & 63;
  const int wid = tid >> 6;
  const int wm = wid >> 1, wn = wid & 1;
  const int lr = lane & 15;
  const int lg = lane >> 4;            // 0..3 -> which 16B chunk of the 32-k half
  constexpr int WMt = BM / 2, WNt = BN / 2;
  constexpr int MR = WMt / 16, NR = WNt / 16;

  const bf16* Abase = A + (size_t)m0 * K;
  const bf16* Bbase = B + (size_t)n0 * K;

  auto stage = [&](int buf, int k0) {
    #pragma unroll
    for (int i = 0; i < BM / 32; ++i) {
      int c = i * 256 + tid;
      int row = c >> 3, kc = c & 7;
      gload_lds16(Abase + (size_t)row * K + k0 + ((kc ^ (row & 7)) << 3), &sA[buf][c * 8]);
    }
    #pragma unroll
    for (int i = 0; i < BN / 32; ++i) {
      int c = i * 256 + tid;
      int row = c >> 3, kc = c & 7;
      gload_lds16(Bbase + (size_t)row * K + k0 + ((kc ^ (row & 7)) << 3), &sB[buf][c * 8]);
    }
  };

  f32x4 acc[MR][NR] = {};
  __syncthreads();                        // pool free (prev user done)
  stage(0, 0);
  __syncthreads();
  const int nk = K >> 6;
  for (int it = 0; it < nk; ++it) {
    const int cur = it & 1;
    if (it + 1 < nk) stage(cur ^ 1, (it + 1) << 6);
    #pragma unroll
    for (int kk = 0; kk < 2; ++kk) {
      const int jg = kk * 4 + lg;        // global chunk index 0..7
      bf16x8v af[MR], bfv[NR];
      #pragma unroll
      for (int m = 0; m < MR; ++m) {
        int ar = wm * WMt + m * 16 + lr;
        af[m] = *(const bf16x8v*)&sA[cur][ar * 64 + ((jg ^ (ar & 7)) << 3)];
      }
      #pragma unroll
      for (int n = 0; n < NR; ++n) {
        int br = wn * WNt + n * 16 + lr;
        bfv[n] = *(const bf16x8v*)&sB[cur][br * 64 + ((jg ^ (br & 7)) << 3)];
      }
      #pragma unroll
      for (int m = 0; m < MR; ++m)
        #pragma unroll
        for (int n = 0; n < NR; ++n)
          acc[m][n] = __builtin_amdgcn_mfma_f32_16x16x32_bf16(af[m], bfv[n], acc[m][n], 0, 0, 0);
    }
    __syncthreads();
  }

  const int r0 = (lane >> 4) * 4;
  #pragma unroll
  for (int m = 0; m < MR; ++m) {
    #pragma unroll
    for (int n = 0; n < NR; ++n) {
      int gc = n0 + wn * WNt + n * 16 + lr;
      float bv = bias[gc];
      #pragma unroll
      for (int r = 0; r < 4; ++r) {
        int gr = m0 + wm * WMt + m * 16 + r0 + r;
        float v = acc[m][n][r] + bv;
        if (mode == 1)
          ((bf16*)C)[(size_t)gr * N + gc] = __float2bfloat16(v > 0.f ? v : 0.f);
        else
          ((float*)C)[(size_t)gr * N + gc] = v;
      }
    }
  }
}

// ---------------------------------------------------------------------------
// fused W2p GEMM (512x512, K=2048) + posterior softplus/rsample epilogue.
// 64 jobs: mb 0..7 (64 rows), nl 0..7 (32-col strip of BOTH loc and raw).
// sB rows 0..31 = loc cols nl*32..+31; rows 32..63 = raw cols nl*32..+31.
// Swizzled staging/reads as in gemm_tile.
// ---------------------------------------------------------------------------
__device__ void w2p_tile(const bf16* __restrict__ hq, const bf16* __restrict__ W2pT,
                         const float* __restrict__ b2p, const float* __restrict__ eps,
                         float* __restrict__ o_mu, float* __restrict__ o_sd,
                         float* __restrict__ o_st,
                         const float* __restrict__ nt_next,
                         const float* __restrict__ act_next,
                         bf16* __restrict__ xcat, int make_xcat,
                         int blk, int tid, char* pool)
{
  constexpr int K = 2048, NK = K / 64;
  const int mb = blk & 7, nl = blk >> 3;
  const int m0 = mb * 64;
  const int j0 = nl * 32;

  bf16 (*sA)[64 * 64] = (bf16(*)[64 * 64])pool;             // 2 x 8KB
  bf16 (*sB)[64 * 64] = (bf16(*)[64 * 64])(pool + 16384);   // 2 x 8KB
  float* tile = (float*)pool;                                // 16KB reuse

  const int lane = tid & 63;
  const int wid = tid >> 6;
  const int wm = wid >> 1, wn = wid & 1;
  const int lr = lane & 15;
  const int lg = lane >> 4;

  const bf16* Abase = hq + (size_t)m0 * K;

  auto stage = [&](int buf, int k0) {
    #pragma unroll
    for (int i = 0; i < 2; ++i) {      // A: 64 rows
      int c = i * 256 + tid;
      int row = c >> 3, kc = c & 7;
      gload_lds16(Abase + (size_t)row * K + k0 + ((kc ^ (row & 7)) << 3), &sA[buf][c * 8]);
    }
    #pragma unroll
    for (int i = 0; i < 2; ++i) {      // B: 64 rows (loc strip + raw strip)
      int c = i * 256 + tid;
      int row = c >> 3, kc = c & 7;
      int grow = (row < 32) ? (j0 + row) : (224 + j0 + row);  // 256 + j0 + (row-32)
      gload_lds16(W2pT + (size_t)grow * K + k0 + ((kc ^ (row & 7)) << 3), &sB[buf][c * 8]);
    }
  };

  f32x4 acc[2][2] = {};
  __syncthreads();
  stage(0, 0);
  __syncthreads();
  for (int it = 0; it < NK; ++it) {
    const int cur = it & 1;
    if (it + 1 < NK) stage(cur ^ 1, (it + 1) << 6);
    #pragma unroll
    for (int kk = 0; kk < 2; ++kk) {
      const int jg = kk * 4 + lg;
      bf16x8v af[2], bfv[2];
      #pragma unroll
      for (int m = 0; m < 2; ++m) {
        int ar = wm * 32 + m * 16 + lr;
        af[m] = *(const bf16x8v*)&sA[cur][ar * 64 + ((jg ^ (ar & 7)) << 3)];
      }
      #pragma unroll
      for (int n = 0; n < 2; ++n) {
        int br = wn * 32 + n * 16 + lr;
        bfv[n] = *(const bf16x8v*)&sB[cur][br * 64 + ((jg ^ (br & 7)) << 3)];
      }
      #pragma unroll
      for (int m = 0; m < 2; ++m)
        #pragma unroll
        for (int n = 0; n < 2; ++n)
          acc[m][n] = __builtin_amdgcn_mfma_f32_16x16x32_bf16(af[m], bfv[n], acc[m][n], 0, 0, 0);
    }
    __syncthreads();
  }

  // dump acc -> f32 tile [64][64]: col c<32 = loc(j0+c), c>=32 = raw(j0+c-32)
  const int r0 = (lane >> 4) * 4;
  #pragma unroll
  for (int m = 0; m < 2; ++m)
    #pragma unroll
    for (int n = 0; n < 2; ++n) {
      int tc = wn * 32 + n * 16 + lr;
      #pragma unroll
      for (int r = 0; r < 4; ++r)
        tile[(wm * 32 + m * 16 + r0 + r) * 64 + tc] = acc[m][n][r];
    }
  __syncthreads();

  for (int e = tid; e < 64 * 32; e += 256) {
    int rr = e >> 5, cc = e & 31;
    int b = m0 + rr;
    int j = j0 + cc;
    float loc = tile[rr * 64 + cc] + b2p[j];
    float raw = tile[rr * 64 + 32 + cc] + b2p[256 + j];
    float sp = (raw > 20.f) ? raw : log1pf(__expf(raw));
    float scale = sp + 0.1f;
    float st = loc + scale * eps[(size_t)b * 256 + j];
    o_mu[(size_t)b * 256 + j] = loc;
    o_sd[(size_t)b * 256 + j] = scale;
    o_st[(size_t)b * 256 + j] = st;
    if (make_xcat)
      xcat[(size_t)b * 320 + j] = __float2bfloat16(st * nt_next[b]);
  }
  if (make_xcat && nl == 0) {
    for (int e = tid; e < 64 * 64; e += 256) {
      int rr = e >> 6, cc = e & 63;
      int b = m0 + rr;
      xcat[(size_t)b * 320 + 256 + cc] = __float2bfloat16(act_next[(size_t)b * 64 + cc]);
    }
  }
}

// ---------------------------------------------------------------------------
// weight transpose phase: src fp32 [K,N] -> dst bf16 [N,K], grid-stride tiles
// ---------------------------------------------------------------------------
__device__ void transpose_phase(const float* __restrict__ src, bf16* __restrict__ dst,
                                int K, int N, int bid, int tid, float* t /*32x33*/)
{
  const int ntile = (K / 32) * (N / 32);
  const int tx = tid & 31, ty = tid >> 5;   // 32 x 8
  for (int it = bid; it < ntile; it += NB) {
    int kt = it % (K / 32), nt = it / (K / 32);
    int k0 = kt * 32, n0 = nt * 32;
    __syncthreads();
    #pragma unroll
    for (int i = 0; i < 32; i += 8)
      t[(ty + i) * 33 + tx] = src[(size_t)(k0 + ty + i) * N + n0 + tx];
    __syncthreads();
    #pragma unroll
    for (int i = 0; i < 32; i += 8)
      dst[(size_t)(n0 + ty + i) * K + k0 + tx] = __float2bfloat16(t[tx * 33 + ty + i]);
  }
}

__device__ __forceinline__ float sigmoidf_(float x) { return 1.f / (1.f + __expf(-x)); }

__device__ __forceinline__ float gru1(float ir, float hr, float iz, float hz,
                                      float in_, float hn, float bo)
{
  float r = sigmoidf_(ir + hr);
  float z = sigmoidf_(iz + hz);
  float n = tanhf(in_ + r * hn);
  return (1.f - z) * n + z * bo;
}

struct Args {
  const float *prev_state, *actions, *prev_belief, *obs_emb, *nonterm;
  const float *W_embed, *b_embed, *Wi, *bi, *Wh, *bh;
  const float *W1, *b1, *W2, *b2, *W1p, *b1p, *W2p, *b2p;
  const float *eps_p, *eps_q;
  bf16 *WembT, *WiT, *WhT, *W1T, *W2T, *W1pT, *W2pT;
  float* belief_f32; bf16 *belief_b16, *xcat, *hidden;
  float *gi, *gh; bf16 *hqcat, *hq, *belA, *hp; float* yp;
  float* out;
  unsigned* cnt;
};

// ---------------------------------------------------------------------------
__global__ __launch_bounds__(256) void mega(Args a)
{
  extern __shared__ char pool[];        // 64 KB
  const int bid = blockIdx.x;
  const int tid = threadIdx.x;
  const int sj = ((bid & 7) << 5) | (bid >> 3);   // XCD-grouped job id
  unsigned tgt = 0;

  // ---- P0: weight transposes + init belief/xcat ----
  transpose_phase(a.W_embed, a.WembT, 320, 2048, bid, tid, (float*)pool);
  transpose_phase(a.Wi,  a.WiT,  2048, 6144, bid, tid, (float*)pool);
  transpose_phase(a.Wh,  a.WhT,  2048, 6144, bid, tid, (float*)pool);
  transpose_phase(a.W1,  a.W1T,  2048, 2048, bid, tid, (float*)pool);
  transpose_phase(a.W2,  a.W2T,  2048, 512,  bid, tid, (float*)pool);
  transpose_phase(a.W1p, a.W1pT, 3072, 2048, bid, tid, (float*)pool);
  transpose_phase(a.W2p, a.W2pT, 2048, 512,  bid, tid, (float*)pool);
  for (int i = bid * 256 + tid; i < 512 * 2048; i += NB * 256) {
    float v = a.prev_belief[i];
    a.belief_f32[i] = v;
    a.belief_b16[i] = __float2bfloat16(v);
  }
  for (int i = bid * 256 + tid; i < 512 * 320; i += NB * 256) {
    int b = i / 320, c = i - b * 320;
    float v = (c < 256) ? a.prev_state[b * 256 + c] * a.nonterm[b]
                        : a.actions[b * 64 + (c - 256)];
    a.xcat[i] = __float2bfloat16(v);
  }
  gbar(a.cnt, tgt += NB);

  // ---- P1: hidden_0 = relu(xcat @ WembT + b_embed) ----
  gemm_tile<64, 64>(a.xcat, a.WembT, a.b_embed, a.hidden, 2048, 320, 8, 1, sj, tid, pool);
  gbar(a.cnt, tgt += NB);

  for (int t = 0; t < TM1; ++t) {
    // ---- GIGH: gi = hidden@WiT+bi ; gh = belief@WhT+bh ----
    gemm_tile<128, 96>(a.hidden, a.WiT, a.bi, a.gi, 6144, 2048, 4, 0, sj, tid, pool);
    gemm_tile<128, 96>(a.belief_b16, a.WhT, a.bh, a.gh, 6144, 2048, 4, 0, sj, tid, pool);
    gbar(a.cnt, tgt += NB);

    // ---- gru elementwise ----
    {
      const float* obs_t = a.obs_emb + (size_t)t * 512 * 1024;
      float* out_bel = a.out + OUT_BEL + (size_t)t * 512 * 2048;
      for (int i = bid * 256 + tid; i < 512 * 2048 / 4; i += NB * 256) {
        int b = i >> 9;
        int c = (i & 511) * 4;
        size_t gb = (size_t)b * 6144;
        float4 ir = *(const float4*)&a.gi[gb + c];
        float4 iz = *(const float4*)&a.gi[gb + 2048 + c];
        float4 in_ = *(const float4*)&a.gi[gb + 4096 + c];
        float4 hr = *(const float4*)&a.gh[gb + c];
        float4 hz = *(const float4*)&a.gh[gb + 2048 + c];
        float4 hn = *(const float4*)&a.gh[gb + 4096 + c];
        float4 bo = *(const float4*)&a.belief_f32[(size_t)b * 2048 + c];
        float4 nb;
        nb.x = gru1(ir.x, hr.x, iz.x, hz.x, in_.x, hn.x, bo.x);
        nb.y = gru1(ir.y, hr.y, iz.y, hz.y, in_.y, hn.y, bo.y);
        nb.z = gru1(ir.z, hr.z, iz.z, hz.z, in_.z, hn.z, bo.z);
        nb.w = gru1(ir.w, hr.w, iz.w, hz.w, in_.w, hn.w, bo.w);
        *(float4*)&a.belief_f32[(size_t)b * 2048 + c] = nb;
        *(float4*)&out_bel[(size_t)b * 2048 + c] = nb;
        ushort4 u; u.x = bfb(nb.x); u.y = bfb(nb.y); u.z = bfb(nb.z); u.w = bfb(nb.w);
        *(ushort4*)&a.belief_b16[(size_t)b * 2048 + c] = u;
        *(ushort4*)&a.hqcat[(size_t)b * 3072 + c] = u;
        if ((i & 511) < 256) {
          float4 ov = *(const float4*)&obs_t[(size_t)b * 1024 + c];
          ushort4 uo; uo.x = bfb(ov.x); uo.y = bfb(ov.y); uo.z = bfb(ov.z); uo.w = bfb(ov.w);
          *(ushort4*)&a.hqcat[(size_t)b * 3072 + 2048 + c] = uo;
        }
      }
    }
    gbar(a.cnt, tgt += NB);

    // ---- W1p: hq = relu(hqcat @ W1pT + b1p), K=3072 ----
    gemm_tile<64, 64>(a.hqcat, a.W1pT, a.b1p, a.hq, 2048, 3072, 8, 1, sj, tid, pool);
    gbar(a.cnt, tgt += NB);

    // ---- fused W2p + posterior sample + next xcat ----
    {
      int tn = (t < TM1 - 1) ? t + 1 : t;
      if (bid < 64)
        w2p_tile(a.hq, a.W2pT, a.b2p,
                 a.eps_q + (size_t)t * 512 * 256,
                 a.out + OUT_QMU + (size_t)t * 512 * 256,
                 a.out + OUT_QSD + (size_t)t * 512 * 256,
                 a.out + OUT_QST + (size_t)t * 512 * 256,
                 a.nonterm + (size_t)tn * 512,
                 a.actions + (size_t)tn * 512 * 64,
                 a.xcat, (t < TM1 - 1) ? 1 : 0, bid, tid, pool);
    }
    gbar(a.cnt, tgt += NB);

    // ---- embed: hidden_{t+1} = relu(xcat @ WembT + b_embed) ----
    if (t < TM1 - 1) {
      gemm_tile<64, 64>(a.xcat, a.WembT, a.b_embed, a.hidden, 2048, 320, 8, 1, sj, tid, pool);
      gbar(a.cnt, tgt += NB);
    }
  }

  // ---- batched prior: 8 chunks of 4096 rows ----
  for (int c = 0; c < 8; ++c) {
    const float* bsrc = a.out + OUT_BEL + (size_t)c * 4096 * 2048;
    for (int i = bid * 256 + tid; i < 4096 * 2048 / 4; i += NB * 256) {
      float4 v = *(const float4*)&bsrc[i * 4];
      ushort4 u; u.x = bfb(v.x); u.y = bfb(v.y); u.z = bfb(v.z); u.w = bfb(v.w);
      *(ushort4*)&a.belA[i * 4] = u;
    }
    gbar(a.cnt, tgt += NB);

    // hp = relu(belA @ W1T + b1): 512 jobs of 128x128, 2 rounds
    gemm_tile<128, 128>(a.belA, a.W1T, a.b1, a.hp, 2048, 2048, 32, 1, sj, tid, pool);
    gemm_tile<128, 128>(a.belA, a.W1T, a.b1, a.hp, 2048, 2048, 32, 1, sj + 256, tid, pool);
    gbar(a.cnt, tgt += NB);

    // yp = hp @ W2T + b2: 512 jobs of 64x64, 2 rounds
    gemm_tile<64, 64>(a.hp, a.W2T, a.b2, a.yp, 512, 2048, 64, 0, sj, tid, pool);
    gemm_tile<64, 64>(a.hp, a.W2T, a.b2, a.yp, 512, 2048, 64, 0, sj + 256, tid, pool);
    gbar(a.cnt, tgt += NB);

    for (int i = bid * 256 + tid; i < 4096 * 256; i += NB * 256) {
      int r = i >> 8, j = i & 255;
      float loc = a.yp[(size_t)r * 512 + j];
      float raw = a.yp[(size_t)r * 512 + 256 + j];
      float sp = (raw > 20.f) ? raw : log1pf(__expf(raw));
      float scale = sp + 0.1f;
      size_t o = (size_t)c * 4096 * 256 + i;
      a.out[OUT_PMU + o] = loc;
      a.out[OUT_PSD + o] = scale;
      a.out[OUT_PST + o] = loc + scale * a.eps_p[o];
    }
    gbar(a.cnt, tgt += NB);
  }
}

// ---------------------------------------------------------------------------
extern "C" void kernel_launch(void* const* d_in, const int* in_sizes, int n_in,
                              void* d_out, int out_size, void* d_ws, size_t ws_size,
                              hipStream_t stream)
{
  (void)in_sizes; (void)n_in; (void)out_size; (void)ws_size;
  Args a;
  a.prev_state = (const float*)d_in[0];
  a.actions    = (const float*)d_in[1];
  a.prev_belief= (const float*)d_in[2];
  a.obs_emb    = (const float*)d_in[3];
  a.nonterm    = (const float*)d_in[4];
  a.W_embed    = (const float*)d_in[5];
  a.b_embed    = (const float*)d_in[6];
  a.Wi         = (const float*)d_in[7];
  a.bi         = (const float*)d_in[8];
  a.Wh         = (const float*)d_in[9];
  a.bh         = (const float*)d_in[10];
  a.W1         = (const float*)d_in[11];
  a.b1         = (const float*)d_in[12];
  a.W2         = (const float*)d_in[13];
  a.b2         = (const float*)d_in[14];
  a.W1p        = (const float*)d_in[15];
  a.b1p        = (const float*)d_in[16];
  a.W2p        = (const float*)d_in[17];
  a.b2p        = (const float*)d_in[18];
  a.eps_p      = (const float*)d_in[19];
  a.eps_q      = (const float*)d_in[20];
  a.out        = (float*)d_out;

  char* ws = (char*)d_ws;
  size_t off = 0;
  auto alloc = [&](size_t bytes) -> char* {
    char* p = ws + off;
    off = (off + bytes + 255) & ~(size_t)255;
    return p;
  };
  a.cnt        = (unsigned*)alloc(256);
  a.WembT      = (bf16*)alloc((size_t)2048 * 320 * 2);
  a.WiT        = (bf16*)alloc((size_t)6144 * 2048 * 2);
  a.WhT        = (bf16*)alloc((size_t)6144 * 2048 * 2);
  a.W1T        = (bf16*)alloc((size_t)2048 * 2048 * 2);
  a.W2T        = (bf16*)alloc((size_t)512 * 2048 * 2);
  a.W1pT       = (bf16*)alloc((size_t)2048 * 3072 * 2);
  a.W2pT       = (bf16*)alloc((size_t)512 * 2048 * 2);
  a.belief_f32 = (float*)alloc((size_t)512 * 2048 * 4);
  a.belief_b16 = (bf16*)alloc((size_t)512 * 2048 * 2);
  a.xcat       = (bf16*)alloc((size_t)512 * 320 * 2);
  a.hidden     = (bf16*)alloc((size_t)512 * 2048 * 2);
  a.gi         = (float*)alloc((size_t)512 * 6144 * 4);
  a.gh         = (float*)alloc((size_t)512 * 6144 * 4);
  a.hqcat      = (bf16*)alloc((size_t)512 * 3072 * 2);
  a.hq         = (bf16*)alloc((size_t)512 * 2048 * 2);
  a.belA       = (bf16*)alloc((size_t)4096 * 2048 * 2);
  a.hp         = (bf16*)alloc((size_t)4096 * 2048 * 2);
  a.yp         = (float*)alloc((size_t)4096 * 512 * 4);

  hipMemsetAsync(a.cnt, 0, 256, stream);
  mega<<<NB, 256, 65536, stream>>>(a);
}

// Round 6
// 12387.440 us; speedup vs baseline: 1.3729x; 1.2341x over previous
//
#include <hip/hip_runtime.h>
#include <hip/hip_bf16.h>
#include <cstdint>

typedef __hip_bfloat16 bf16;
typedef __attribute__((ext_vector_type(8))) short bf16x8v;   // 8 bf16 in 4 VGPRs
typedef __attribute__((ext_vector_type(4))) float f32x4;

#define NB 256          // persistent blocks (1 per CU; all co-resident)
#define TM1 64
#define BATCH 512

// output offsets (elements) in d_out, per reference return order
#define OUT_BEL  ((size_t)0)
#define OUT_PST  ((size_t)67108864)   // prior_states
#define OUT_PMU  ((size_t)75497472)   // prior_means
#define OUT_PSD  ((size_t)83886080)   // prior_std_devs
#define OUT_QST  ((size_t)92274688)   // posterior_states
#define OUT_QMU  ((size_t)100663296)  // posterior_means
#define OUT_QSD  ((size_t)109051904)  // posterior_std_devs

__device__ __forceinline__ void gload_lds16(const bf16* g, bf16* l) {
  __builtin_amdgcn_global_load_lds(
      (const __attribute__((address_space(1))) unsigned int*)g,
      (__attribute__((address_space(3))) unsigned int*)l, 16, 0, 0);
}

__device__ __forceinline__ unsigned short bfb(float f) {
  bf16 h = __float2bfloat16(f);
  return *reinterpret_cast<unsigned short*>(&h);
}

// ---------------------------------------------------------------------------
// hierarchical device-scope grid barrier (epoch-monotone, memset-zeroed).
// layout in `bars` (uints, 64B lines): cnt[g] = bars[16*g] (g=bid&7),
// rel[g] = bars[128 + 16*g].  Arrivals hit per-group lines (32 each, mostly
// XCD-local under round-robin dispatch); block 0 aggregates and releases.
// ---------------------------------------------------------------------------
__device__ __forceinline__ void gbar(unsigned* bars, unsigned e, int bid) {
  __syncthreads();
  const int g = bid & 7;
  const int tid = threadIdx.x;
  if (tid == 0) {
    __threadfence();   // release: prior writes device-visible before arrival
    __hip_atomic_fetch_add(&bars[16 * g], 1u, __ATOMIC_RELAXED, __HIP_MEMORY_SCOPE_AGENT);
  }
  if (bid == 0) {
    if (tid < 8) {
      while (__hip_atomic_load(&bars[16 * tid], __ATOMIC_RELAXED, __HIP_MEMORY_SCOPE_AGENT) < 32u * e)
        __builtin_amdgcn_s_sleep(1);
    }
    __syncthreads();   // all 8 groups complete
    if (tid < 8)
      __hip_atomic_store(&bars[128 + 16 * tid], e, __ATOMIC_RELAXED, __HIP_MEMORY_SCOPE_AGENT);
  } else if (tid == 0) {
    while (__hip_atomic_load(&bars[128 + 16 * g], __ATOMIC_RELAXED, __HIP_MEMORY_SCOPE_AGENT) < e)
      __builtin_amdgcn_s_sleep(2);
  }
  if (tid == 0) __threadfence();   // acquire: drop stale cached lines
  __syncthreads();
}

// ---------------------------------------------------------------------------
// one GEMM output tile: C[M,N] = A[M,K](bf16,row) @ B[N,K](bf16,row)^T + bias
// 2-phase LDS double-buffer (stage t+1 issued before compute t, one sync/iter)
// T2 bank-conflict fix: 16B-chunk index XOR'd with (row&7) — applied on the
// GLOBAL source address at stage time (LDS dest stays linear, rule #21) and
// on the ds_read address at use time.
// mode 0: C fp32. mode 1: C bf16 + relu. job decode: m fastest.
// ---------------------------------------------------------------------------
template<int BM, int BN>
__device__ void gemm_tile(const bf16* __restrict__ A, const bf16* __restrict__ B,
                          const float* __restrict__ bias, void* __restrict__ C,
                          int N, int K, int nm, int mode, int job, int tid,
                          char* pool)
{
  bf16 (*sA)[BM * 64] = (bf16(*)[BM * 64])pool;
  bf16 (*sB)[BN * 64] = (bf16(*)[BN * 64])(pool + 2 * BM * 64 * 2);

  const int m0 = (job % nm) * BM;
  const int n0 = (job / nm) * BN;
  const int lane = tid & 63;
  const int wid = tid >> 6;
  const int wm = wid >> 1, wn = wid & 1;
  const int lr = lane & 15;
  const int lg = lane >> 4;            // 0..3 -> which 16B chunk of the 32-k half
  constexpr int WMt = BM / 2, WNt = BN / 2;
  constexpr int MR = WMt / 16, NR = WNt / 16;

  const bf16* Abase = A + (size_t)m0 * K;
  const bf16* Bbase = B + (size_t)n0 * K;

  auto stage = [&](int buf, int k0) {
    #pragma unroll
    for (int i = 0; i < BM / 32; ++i) {
      int c = i * 256 + tid;
      int row = c >> 3, kc = c & 7;
      gload_lds16(Abase + (size_t)row * K + k0 + ((kc ^ (row & 7)) << 3), &sA[buf][c * 8]);
    }
    #pragma unroll
    for (int i = 0; i < BN / 32; ++i) {
      int c = i * 256 + tid;
      int row = c >> 3, kc = c & 7;
      gload_lds16(Bbase + (size_t)row * K + k0 + ((kc ^ (row & 7)) << 3), &sB[buf][c * 8]);
    }
  };

  f32x4 acc[MR][NR] = {};
  __syncthreads();                        // pool free (prev user done)
  stage(0, 0);
  __syncthreads();
  const int nk = K >> 6;
  for (int it = 0; it < nk; ++it) {
    const int cur = it & 1;
    if (it + 1 < nk) stage(cur ^ 1, (it + 1) << 6);
    #pragma unroll
    for (int kk = 0; kk < 2; ++kk) {
      const int jg = kk * 4 + lg;        // global chunk index 0..7
      bf16x8v af[MR], bfv[NR];
      #pragma unroll
      for (int m = 0; m < MR; ++m) {
        int ar = wm * WMt + m * 16 + lr;
        af[m] = *(const bf16x8v*)&sA[cur][ar * 64 + ((jg ^ (ar & 7)) << 3)];
      }
      #pragma unroll
      for (int n = 0; n < NR; ++n) {
        int br = wn * WNt + n * 16 + lr;
        bfv[n] = *(const bf16x8v*)&sB[cur][br * 64 + ((jg ^ (br & 7)) << 3)];
      }
      #pragma unroll
      for (int m = 0; m < MR; ++m)
        #pragma unroll
        for (int n = 0; n < NR; ++n)
          acc[m][n] = __builtin_amdgcn_mfma_f32_16x16x32_bf16(af[m], bfv[n], acc[m][n], 0, 0, 0);
    }
    __syncthreads();
  }

  const int r0 = (lane >> 4) * 4;
  #pragma unroll
  for (int m = 0; m < MR; ++m) {
    #pragma unroll
    for (int n = 0; n < NR; ++n) {
      int gc = n0 + wn * WNt + n * 16 + lr;
      float bv = bias[gc];
      #pragma unroll
      for (int r = 0; r < 4; ++r) {
        int gr = m0 + wm * WMt + m * 16 + r0 + r;
        float v = acc[m][n][r] + bv;
        if (mode == 1)
          ((bf16*)C)[(size_t)gr * N + gc] = __float2bfloat16(v > 0.f ? v : 0.f);
        else
          ((float*)C)[(size_t)gr * N + gc] = v;
      }
    }
  }
}

// ---------------------------------------------------------------------------
// fused W2p GEMM (512x512, K=2048) + posterior softplus/rsample epilogue.
// 64 jobs: mb 0..7 (64 rows), nl 0..7 (32-col strip of BOTH loc and raw).
// sB rows 0..31 = loc cols nl*32..+31; rows 32..63 = raw cols nl*32..+31.
// Swizzled staging/reads as in gemm_tile.
// ---------------------------------------------------------------------------
__device__ void w2p_tile(const bf16* __restrict__ hq, const bf16* __restrict__ W2pT,
                         const float* __restrict__ b2p, const float* __restrict__ eps,
                         float* __restrict__ o_mu, float* __restrict__ o_sd,
                         float* __restrict__ o_st,
                         const float* __restrict__ nt_next,
                         const float* __restrict__ act_next,
                         bf16* __restrict__ xcat, int make_xcat,
                         int blk, int tid, char* pool)
{
  constexpr int K = 2048, NK = K / 64;
  const int mb = blk & 7, nl = blk >> 3;
  const int m0 = mb * 64;
  const int j0 = nl * 32;

  bf16 (*sA)[64 * 64] = (bf16(*)[64 * 64])pool;             // 2 x 8KB
  bf16 (*sB)[64 * 64] = (bf16(*)[64 * 64])(pool + 16384);   // 2 x 8KB
  float* tile = (float*)pool;                                // 16KB reuse

  const int lane = tid & 63;
  const int wid = tid >> 6;
  const int wm = wid >> 1, wn = wid & 1;
  const int lr = lane & 15;
  const int lg = lane >> 4;

  const bf16* Abase = hq + (size_t)m0 * K;

  auto stage = [&](int buf, int k0) {
    #pragma unroll
    for (int i = 0; i < 2; ++i) {      // A: 64 rows
      int c = i * 256 + tid;
      int row = c >> 3, kc = c & 7;
      gload_lds16(Abase + (size_t)row * K + k0 + ((kc ^ (row & 7)) << 3), &sA[buf][c * 8]);
    }
    #pragma unroll
    for (int i = 0; i < 2; ++i) {      // B: 64 rows (loc strip + raw strip)
      int c = i * 256 + tid;
      int row = c >> 3, kc = c & 7;
      int grow = (row < 32) ? (j0 + row) : (224 + j0 + row);  // 256 + j0 + (row-32)
      gload_lds16(W2pT + (size_t)grow * K + k0 + ((kc ^ (row & 7)) << 3), &sB[buf][c * 8]);
    }
  };

  f32x4 acc[2][2] = {};
  __syncthreads();
  stage(0, 0);
  __syncthreads();
  for (int it = 0; it < NK; ++it) {
    const int cur = it & 1;
    if (it + 1 < NK) stage(cur ^ 1, (it + 1) << 6);
    #pragma unroll
    for (int kk = 0; kk < 2; ++kk) {
      const int jg = kk * 4 + lg;
      bf16x8v af[2], bfv[2];
      #pragma unroll
      for (int m = 0; m < 2; ++m) {
        int ar = wm * 32 + m * 16 + lr;
        af[m] = *(const bf16x8v*)&sA[cur][ar * 64 + ((jg ^ (ar & 7)) << 3)];
      }
      #pragma unroll
      for (int n = 0; n < 2; ++n) {
        int br = wn * 32 + n * 16 + lr;
        bfv[n] = *(const bf16x8v*)&sB[cur][br * 64 + ((jg ^ (br & 7)) << 3)];
      }
      #pragma unroll
      for (int m = 0; m < 2; ++m)
        #pragma unroll
        for (int n = 0; n < 2; ++n)
          acc[m][n] = __builtin_amdgcn_mfma_f32_16x16x32_bf16(af[m], bfv[n], acc[m][n], 0, 0, 0);
    }
    __syncthreads();
  }

  // dump acc -> f32 tile [64][64]: col c<32 = loc(j0+c), c>=32 = raw(j0+c-32)
  const int r0 = (lane >> 4) * 4;
  #pragma unroll
  for (int m = 0; m < 2; ++m)
    #pragma unroll
    for (int n = 0; n < 2; ++n) {
      int tc = wn * 32 + n * 16 + lr;
      #pragma unroll
      for (int r = 0; r < 4; ++r)
        tile[(wm * 32 + m * 16 + r0 + r) * 64 + tc] = acc[m][n][r];
    }
  __syncthreads();

  for (int e = tid; e < 64 * 32; e += 256) {
    int rr = e >> 5, cc = e & 31;
    int b = m0 + rr;
    int j = j0 + cc;
    float loc = tile[rr * 64 + cc] + b2p[j];
    float raw = tile[rr * 64 + 32 + cc] + b2p[256 + j];
    float sp = (raw > 20.f) ? raw : log1pf(__expf(raw));
    float scale = sp + 0.1f;
    float st = loc + scale * eps[(size_t)b * 256 + j];
    o_mu[(size_t)b * 256 + j] = loc;
    o_sd[(size_t)b * 256 + j] = scale;
    o_st[(size_t)b * 256 + j] = st;
    if (make_xcat)
      xcat[(size_t)b * 320 + j] = __float2bfloat16(st * nt_next[b]);
  }
  if (make_xcat && nl == 0) {
    for (int e = tid; e < 64 * 64; e += 256) {
      int rr = e >> 6, cc = e & 63;
      int b = m0 + rr;
      xcat[(size_t)b * 320 + 256 + cc] = __float2bfloat16(act_next[(size_t)b * 64 + cc]);
    }
  }
}

// ---------------------------------------------------------------------------
// weight transpose phase: src fp32 [K,N] -> dst bf16 [N,K], grid-stride tiles
// ---------------------------------------------------------------------------
__device__ void transpose_phase(const float* __restrict__ src, bf16* __restrict__ dst,
                                int K, int N, int bid, int tid, float* t /*32x33*/)
{
  const int ntile = (K / 32) * (N / 32);
  const int tx = tid & 31, ty = tid >> 5;   // 32 x 8
  for (int it = bid; it < ntile; it += NB) {
    int kt = it % (K / 32), nt = it / (K / 32);
    int k0 = kt * 32, n0 = nt * 32;
    __syncthreads();
    #pragma unroll
    for (int i = 0; i < 32; i += 8)
      t[(ty + i) * 33 + tx] = src[(size_t)(k0 + ty + i) * N + n0 + tx];
    __syncthreads();
    #pragma unroll
    for (int i = 0; i < 32; i += 8)
      dst[(size_t)(n0 + ty + i) * K + k0 + tx] = __float2bfloat16(t[tx * 33 + ty + i]);
  }
}

__device__ __forceinline__ float sigmoidf_(float x) { return 1.f / (1.f + __expf(-x)); }

__device__ __forceinline__ float gru1(float ir, float hr, float iz, float hz,
                                      float in_, float hn, float bo)
{
  float r = sigmoidf_(ir + hr);
  float z = sigmoidf_(iz + hz);
  float n = tanhf(in_ + r * hn);
  return (1.f - z) * n + z * bo;
}

struct Args {
  const float *prev_state, *actions, *prev_belief, *obs_emb, *nonterm;
  const float *W_embed, *b_embed, *Wi, *bi, *Wh, *bh;
  const float *W1, *b1, *W2, *b2, *W1p, *b1p, *W2p, *b2p;
  const float *eps_p, *eps_q;
  bf16 *WembT, *WiT, *WhT, *W1T, *W2T, *W1pT, *W2pT;
  float* belief_f32; bf16 *belief_b16, *xcat, *hidden;
  float *gi, *gh; bf16 *hqcat, *hq, *belA, *hp; float* yp;
  float* out;
  unsigned* cnt;
};

// ---------------------------------------------------------------------------
__global__ __launch_bounds__(256) void mega(Args a)
{
  extern __shared__ char pool[];        // 64 KB
  const int bid = blockIdx.x;
  const int tid = threadIdx.x;
  const int sj = ((bid & 7) << 5) | (bid >> 3);   // XCD-grouped job id
  unsigned ep = 0;

  // ---- P0: weight transposes + init belief/xcat ----
  transpose_phase(a.W_embed, a.WembT, 320, 2048, bid, tid, (float*)pool);
  transpose_phase(a.Wi,  a.WiT,  2048, 6144, bid, tid, (float*)pool);
  transpose_phase(a.Wh,  a.WhT,  2048, 6144, bid, tid, (float*)pool);
  transpose_phase(a.W1,  a.W1T,  2048, 2048, bid, tid, (float*)pool);
  transpose_phase(a.W2,  a.W2T,  2048, 512,  bid, tid, (float*)pool);
  transpose_phase(a.W1p, a.W1pT, 3072, 2048, bid, tid, (float*)pool);
  transpose_phase(a.W2p, a.W2pT, 2048, 512,  bid, tid, (float*)pool);
  for (int i = bid * 256 + tid; i < 512 * 2048; i += NB * 256) {
    float v = a.prev_belief[i];
    a.belief_f32[i] = v;
    a.belief_b16[i] = __float2bfloat16(v);
  }
  for (int i = bid * 256 + tid; i < 512 * 320; i += NB * 256) {
    int b = i / 320, c = i - b * 320;
    float v = (c < 256) ? a.prev_state[b * 256 + c] * a.nonterm[b]
                        : a.actions[b * 64 + (c - 256)];
    a.xcat[i] = __float2bfloat16(v);
  }
  gbar(a.cnt, ++ep, bid);

  // ---- P1: hidden_0 = relu(xcat @ WembT + b_embed) ----
  gemm_tile<64, 64>(a.xcat, a.WembT, a.b_embed, a.hidden, 2048, 320, 8, 1, sj, tid, pool);
  gbar(a.cnt, ++ep, bid);

  for (int t = 0; t < TM1; ++t) {
    // ---- GIGH: gi = hidden@WiT+bi ; gh = belief@WhT+bh ----
    gemm_tile<128, 96>(a.hidden, a.WiT, a.bi, a.gi, 6144, 2048, 4, 0, sj, tid, pool);
    gemm_tile<128, 96>(a.belief_b16, a.WhT, a.bh, a.gh, 6144, 2048, 4, 0, sj, tid, pool);
    gbar(a.cnt, ++ep, bid);

    // ---- gru elementwise ----
    {
      const float* obs_t = a.obs_emb + (size_t)t * 512 * 1024;
      float* out_bel = a.out + OUT_BEL + (size_t)t * 512 * 2048;
      for (int i = bid * 256 + tid; i < 512 * 2048 / 4; i += NB * 256) {
        int b = i >> 9;
        int c = (i & 511) * 4;
        size_t gb = (size_t)b * 6144;
        float4 ir = *(const float4*)&a.gi[gb + c];
        float4 iz = *(const float4*)&a.gi[gb + 2048 + c];
        float4 in_ = *(const float4*)&a.gi[gb + 4096 + c];
        float4 hr = *(const float4*)&a.gh[gb + c];
        float4 hz = *(const float4*)&a.gh[gb + 2048 + c];
        float4 hn = *(const float4*)&a.gh[gb + 4096 + c];
        float4 bo = *(const float4*)&a.belief_f32[(size_t)b * 2048 + c];
        float4 nb;
        nb.x = gru1(ir.x, hr.x, iz.x, hz.x, in_.x, hn.x, bo.x);
        nb.y = gru1(ir.y, hr.y, iz.y, hz.y, in_.y, hn.y, bo.y);
        nb.z = gru1(ir.z, hr.z, iz.z, hz.z, in_.z, hn.z, bo.z);
        nb.w = gru1(ir.w, hr.w, iz.w, hz.w, in_.w, hn.w, bo.w);
        *(float4*)&a.belief_f32[(size_t)b * 2048 + c] = nb;
        *(float4*)&out_bel[(size_t)b * 2048 + c] = nb;
        ushort4 u; u.x = bfb(nb.x); u.y = bfb(nb.y); u.z = bfb(nb.z); u.w = bfb(nb.w);
        *(ushort4*)&a.belief_b16[(size_t)b * 2048 + c] = u;
        *(ushort4*)&a.hqcat[(size_t)b * 3072 + c] = u;
        if ((i & 511) < 256) {
          float4 ov = *(const float4*)&obs_t[(size_t)b * 1024 + c];
          ushort4 uo; uo.x = bfb(ov.x); uo.y = bfb(ov.y); uo.z = bfb(ov.z); uo.w = bfb(ov.w);
          *(ushort4*)&a.hqcat[(size_t)b * 3072 + 2048 + c] = uo;
        }
      }
    }
    gbar(a.cnt, ++ep, bid);

    // ---- W1p: hq = relu(hqcat @ W1pT + b1p), K=3072 ----
    gemm_tile<64, 64>(a.hqcat, a.W1pT, a.b1p, a.hq, 2048, 3072, 8, 1, sj, tid, pool);
    gbar(a.cnt, ++ep, bid);

    // ---- fused W2p + posterior sample + next xcat ----
    {
      int tn = (t < TM1 - 1) ? t + 1 : t;
      if (bid < 64)
        w2p_tile(a.hq, a.W2pT, a.b2p,
                 a.eps_q + (size_t)t * 512 * 256,
                 a.out + OUT_QMU + (size_t)t * 512 * 256,
                 a.out + OUT_QSD + (size_t)t * 512 * 256,
                 a.out + OUT_QST + (size_t)t * 512 * 256,
                 a.nonterm + (size_t)tn * 512,
                 a.actions + (size_t)tn * 512 * 64,
                 a.xcat, (t < TM1 - 1) ? 1 : 0, bid, tid, pool);
    }
    gbar(a.cnt, ++ep, bid);

    // ---- embed: hidden_{t+1} = relu(xcat @ WembT + b_embed) ----
    if (t < TM1 - 1) {
      gemm_tile<64, 64>(a.xcat, a.WembT, a.b_embed, a.hidden, 2048, 320, 8, 1, sj, tid, pool);
      gbar(a.cnt, ++ep, bid);
    }
  }

  // ---- batched prior: 8 chunks of 4096 rows ----
  for (int c = 0; c < 8; ++c) {
    const float* bsrc = a.out + OUT_BEL + (size_t)c * 4096 * 2048;
    for (int i = bid * 256 + tid; i < 4096 * 2048 / 4; i += NB * 256) {
      float4 v = *(const float4*)&bsrc[i * 4];
      ushort4 u; u.x = bfb(v.x); u.y = bfb(v.y); u.z = bfb(v.z); u.w = bfb(v.w);
      *(ushort4*)&a.belA[i * 4] = u;
    }
    gbar(a.cnt, ++ep, bid);

    // hp = relu(belA @ W1T + b1): 512 jobs of 128x128, 2 rounds
    gemm_tile<128, 128>(a.belA, a.W1T, a.b1, a.hp, 2048, 2048, 32, 1, sj, tid, pool);
    gemm_tile<128, 128>(a.belA, a.W1T, a.b1, a.hp, 2048, 2048, 32, 1, sj + 256, tid, pool);
    gbar(a.cnt, ++ep, bid);

    // yp = hp @ W2T + b2: 512 jobs of 64x64, 2 rounds
    gemm_tile<64, 64>(a.hp, a.W2T, a.b2, a.yp, 512, 2048, 64, 0, sj, tid, pool);
    gemm_tile<64, 64>(a.hp, a.W2T, a.b2, a.yp, 512, 2048, 64, 0, sj + 256, tid, pool);
    gbar(a.cnt, ++ep, bid);

    for (int i = bid * 256 + tid; i < 4096 * 256; i += NB * 256) {
      int r = i >> 8, j = i & 255;
      float loc = a.yp[(size_t)r * 512 + j];
      float raw = a.yp[(size_t)r * 512 + 256 + j];
      float sp = (raw > 20.f) ? raw : log1pf(__expf(raw));
      float scale = sp + 0.1f;
      size_t o = (size_t)c * 4096 * 256 + i;
      a.out[OUT_PMU + o] = loc;
      a.out[OUT_PSD + o] = scale;
      a.out[OUT_PST + o] = loc + scale * a.eps_p[o];
    }
    gbar(a.cnt, ++ep, bid);
  }
}

// ---------------------------------------------------------------------------
extern "C" void kernel_launch(void* const* d_in, const int* in_sizes, int n_in,
                              void* d_out, int out_size, void* d_ws, size_t ws_size,
                              hipStream_t stream)
{
  (void)in_sizes; (void)n_in; (void)out_size; (void)ws_size;
  Args a;
  a.prev_state = (const float*)d_in[0];
  a.actions    = (const float*)d_in[1];
  a.prev_belief= (const float*)d_in[2];
  a.obs_emb    = (const float*)d_in[3];
  a.nonterm    = (const float*)d_in[4];
  a.W_embed    = (const float*)d_in[5];
  a.b_embed    = (const float*)d_in[6];
  a.Wi         = (const float*)d_in[7];
  a.bi         = (const float*)d_in[8];
  a.Wh         = (const float*)d_in[9];
  a.bh         = (const float*)d_in[10];
  a.W1         = (const float*)d_in[11];
  a.b1         = (const float*)d_in[12];
  a.W2         = (const float*)d_in[13];
  a.b2         = (const float*)d_in[14];
  a.W1p        = (const float*)d_in[15];
  a.b1p        = (const float*)d_in[16];
  a.W2p        = (const float*)d_in[17];
  a.b2p        = (const float*)d_in[18];
  a.eps_p      = (const float*)d_in[19];
  a.eps_q      = (const float*)d_in[20];
  a.out        = (float*)d_out;

  char* ws = (char*)d_ws;
  size_t off = 0;
  auto alloc = [&](size_t bytes) -> char* {
    char* p = ws + off;
    off = (off + bytes + 255) & ~(size_t)255;
    return p;
  };
  a.cnt        = (unsigned*)alloc(4096);
  a.WembT      = (bf16*)alloc((size_t)2048 * 320 * 2);
  a.WiT        = (bf16*)alloc((size_t)6144 * 2048 * 2);
  a.WhT        = (bf16*)alloc((size_t)6144 * 2048 * 2);
  a.W1T        = (bf16*)alloc((size_t)2048 * 2048 * 2);
  a.W2T        = (bf16*)alloc((size_t)512 * 2048 * 2);
  a.W1pT       = (bf16*)alloc((size_t)2048 * 3072 * 2);
  a.W2pT       = (bf16*)alloc((size_t)512 * 2048 * 2);
  a.belief_f32 = (float*)alloc((size_t)512 * 2048 * 4);
  a.belief_b16 = (bf16*)alloc((size_t)512 * 2048 * 2);
  a.xcat       = (bf16*)alloc((size_t)512 * 320 * 2);
  a.hidden     = (bf16*)alloc((size_t)512 * 2048 * 2);
  a.gi         = (float*)alloc((size_t)512 * 6144 * 4);
  a.gh         = (float*)alloc((size_t)512 * 6144 * 4);
  a.hqcat      = (bf16*)alloc((size_t)512 * 3072 * 2);
  a.hq         = (bf16*)alloc((size_t)512 * 2048 * 2);
  a.belA       = (bf16*)alloc((size_t)4096 * 2048 * 2);
  a.hp         = (bf16*)alloc((size_t)4096 * 2048 * 2);
  a.yp         = (float*)alloc((size_t)4096 * 512 * 4);

  hipMemsetAsync(a.cnt, 0, 4096, stream);
  mega<<<NB, 256, 65536, stream>>>(a);
}